// Round 1
// baseline (1994.700 us; speedup 1.0000x reference)
//
#include <hip/hip_runtime.h>
#include <math.h>

static constexpr int IN_DIM_C  = 256;
static constexpr int HID_DIM_C = 256;
static constexpr int OUT_DIM_C = 64;
static constexpr float EXP_NEG1   = 0.36787944117144233f;
static constexpr float SELU_ALPHA = 1.6732632423543772f;
static constexpr float SELU_SCALE = 1.0507009873554805f;

// ---------------- degree histogram ----------------
__global__ void k_deg(const int* __restrict__ dst, int* __restrict__ deg, int E) {
    int i = blockIdx.x * 256 + threadIdx.x;
    if (i < E) atomicAdd(&deg[dst[i]], 1);
}

// ---------------- hierarchical exclusive scan ----------------
__global__ void k_scan1(const int* __restrict__ deg, int* __restrict__ offs,
                        int* __restrict__ part, int N) {
    __shared__ int sm[256];
    int tid = threadIdx.x, idx = blockIdx.x * 256 + tid;
    int v = (idx < N) ? deg[idx] : 0;
    sm[tid] = v; __syncthreads();
    #pragma unroll
    for (int o = 1; o < 256; o <<= 1) {
        int t = (tid >= o) ? sm[tid - o] : 0;
        __syncthreads();
        sm[tid] += t;
        __syncthreads();
    }
    if (idx < N) offs[idx] = sm[tid] - v;          // exclusive
    if (tid == 255) part[blockIdx.x] = sm[255];    // block total
}

__global__ void k_scan2(int* __restrict__ part, int NB) {
    __shared__ int sm[512];
    int tid = threadIdx.x;
    int v = (tid < NB) ? part[tid] : 0;
    sm[tid] = v; __syncthreads();
    for (int o = 1; o < 512; o <<= 1) {
        int t = (tid >= o) ? sm[tid - o] : 0;
        __syncthreads();
        sm[tid] += t;
        __syncthreads();
    }
    if (tid < NB) part[tid] = sm[tid] - v;         // exclusive over partials
}

__global__ void k_scan3(int* __restrict__ offs, int* __restrict__ cursor,
                        const int* __restrict__ part, int N, int E) {
    int idx = blockIdx.x * 256 + threadIdx.x;
    if (idx < N) {
        int o = offs[idx] + part[idx >> 8];
        offs[idx] = o;
        cursor[idx] = o;
    }
    if (idx == 0) offs[N] = E;
}

// ---------------- CSR fill (incoming edges per dst) ----------------
__global__ void k_fill(const int* __restrict__ src, const int* __restrict__ dst,
                       int* __restrict__ cursor, int* __restrict__ csr, int E) {
    int i = blockIdx.x * 256 + threadIdx.x;
    if (i < E) {
        int d = dst[i];
        int slot = atomicAdd(&cursor[d], 1);
        csr[slot] = src[i];
    }
}

// ---------------- normalization coefficients ----------------
__global__ void k_dinv(const int* __restrict__ deg, float* __restrict__ dinv,
                       float* __restrict__ dinv2, int N) {
    int i = blockIdx.x * 256 + threadIdx.x;
    if (i < N) {
        int d = deg[i];
        dinv[i]  = (d > 0) ? rsqrtf((float)d) : 0.f;
        dinv2[i] = rsqrtf((float)(d + 1));
    }
}

// ---------------- 256-dim aggregation: one wave per node ----------------
__global__ void k_agg256(const float4* __restrict__ xin, float4* __restrict__ yout,
                         const int* __restrict__ offs, const int* __restrict__ csr,
                         const float* __restrict__ dinv, float scl, int N) {
    int gw   = (blockIdx.x * blockDim.x + threadIdx.x) >> 6;  // node
    int lane = threadIdx.x & 63;
    if (gw >= N) return;
    int beg = offs[gw], end = offs[gw + 1];
    float di = dinv[gw];
    float ax = 0.f, ay = 0.f, az = 0.f, aw = 0.f;
    for (int e = beg; e < end; ++e) {
        int s = csr[e];
        float w = di * dinv[s];
        float4 v = xin[s * 64 + lane];
        ax = fmaf(w, v.x, ax); ay = fmaf(w, v.y, ay);
        az = fmaf(w, v.z, az); aw = fmaf(w, v.w, aw);
    }
    float4 r; r.x = ax * scl; r.y = ay * scl; r.z = az * scl; r.w = aw * scl;
    yout[gw * 64 + lane] = r;
}

// ---------------- f32 tiled GEMM: C = A(MxK) * B(KxN) (+bias)(+selu) ----------------
__device__ __forceinline__ float selu_f(float v) {
    return v > 0.f ? SELU_SCALE * v : SELU_SCALE * SELU_ALPHA * expm1f(v);
}

__global__ __launch_bounds__(256) void k_gemm(
        const float* __restrict__ A, const float* __restrict__ B,
        const float* __restrict__ bias, float* __restrict__ C,
        int M, int K, int Ncols, int act) {
    __shared__ float As[16][65];
    __shared__ float Bs[16][64];
    int tid = threadIdx.x;
    int m0 = blockIdx.x * 64;
    int n0 = blockIdx.y * 64;
    int tx = tid & 15, ty = tid >> 4;
    int row0 = ty * 4, col0 = tx * 4;
    int la_r = tid >> 2;          // 0..63 (A row within tile)
    int la_k = (tid & 3) * 4;     // 0,4,8,12
    int lb_k = tid >> 4;          // 0..15
    int lb_n = (tid & 15) * 4;
    float acc[4][4] = {};
    for (int k0 = 0; k0 < K; k0 += 16) {
        float4 av;
        int arow = m0 + la_r;
        if (arow < M) av = *(const float4*)&A[(size_t)arow * K + k0 + la_k];
        else          av = make_float4(0.f, 0.f, 0.f, 0.f);
        float4 bv = *(const float4*)&B[(size_t)(k0 + lb_k) * Ncols + n0 + lb_n];
        __syncthreads();
        As[la_k + 0][la_r] = av.x; As[la_k + 1][la_r] = av.y;
        As[la_k + 2][la_r] = av.z; As[la_k + 3][la_r] = av.w;
        *(float4*)&Bs[lb_k][lb_n] = bv;
        __syncthreads();
        #pragma unroll
        for (int kk = 0; kk < 16; ++kk) {
            float a0 = As[kk][row0 + 0], a1 = As[kk][row0 + 1];
            float a2 = As[kk][row0 + 2], a3 = As[kk][row0 + 3];
            float4 b = *(float4*)&Bs[kk][col0];
            acc[0][0] = fmaf(a0, b.x, acc[0][0]); acc[0][1] = fmaf(a0, b.y, acc[0][1]);
            acc[0][2] = fmaf(a0, b.z, acc[0][2]); acc[0][3] = fmaf(a0, b.w, acc[0][3]);
            acc[1][0] = fmaf(a1, b.x, acc[1][0]); acc[1][1] = fmaf(a1, b.y, acc[1][1]);
            acc[1][2] = fmaf(a1, b.z, acc[1][2]); acc[1][3] = fmaf(a1, b.w, acc[1][3]);
            acc[2][0] = fmaf(a2, b.x, acc[2][0]); acc[2][1] = fmaf(a2, b.y, acc[2][1]);
            acc[2][2] = fmaf(a2, b.z, acc[2][2]); acc[2][3] = fmaf(a2, b.w, acc[2][3]);
            acc[3][0] = fmaf(a3, b.x, acc[3][0]); acc[3][1] = fmaf(a3, b.y, acc[3][1]);
            acc[3][2] = fmaf(a3, b.z, acc[3][2]); acc[3][3] = fmaf(a3, b.w, acc[3][3]);
        }
    }
    #pragma unroll
    for (int i = 0; i < 4; ++i) {
        int row = m0 + row0 + i;
        if (row < M) {
            float4 o;
            o.x = acc[i][0]; o.y = acc[i][1]; o.z = acc[i][2]; o.w = acc[i][3];
            if (bias) {
                o.x += bias[n0 + col0 + 0]; o.y += bias[n0 + col0 + 1];
                o.z += bias[n0 + col0 + 2]; o.w += bias[n0 + col0 + 3];
            }
            if (act) { o.x = selu_f(o.x); o.y = selu_f(o.y); o.z = selu_f(o.z); o.w = selu_f(o.w); }
            *(float4*)&C[(size_t)row * Ncols + n0 + col0] = o;
        }
    }
}

// ---------------- final: 64-dim agg (with self loop) + bias + log_softmax ----------------
__global__ void k_agg64(const float* __restrict__ hw, float* __restrict__ out,
                        const int* __restrict__ offs, const int* __restrict__ csr,
                        const float* __restrict__ dinv2, const float* __restrict__ b2, int N) {
    int gw   = (blockIdx.x * blockDim.x + threadIdx.x) >> 6;
    int lane = threadIdx.x & 63;
    if (gw >= N) return;
    int beg = offs[gw], end = offs[gw + 1];
    float di = dinv2[gw];
    float acc = di * di * hw[(size_t)gw * 64 + lane];      // self loop
    for (int e = beg; e < end; ++e) {
        int s = csr[e];
        acc = fmaf(di * dinv2[s], hw[(size_t)s * 64 + lane], acc);
    }
    acc += b2[lane];
    // log_softmax across the 64 lanes (= the 64 output classes)
    float m = acc;
    #pragma unroll
    for (int o = 32; o > 0; o >>= 1) m = fmaxf(m, __shfl_xor(m, o));
    float ex = expf(acc - m);
    float s = ex;
    #pragma unroll
    for (int o = 32; o > 0; o >>= 1) s += __shfl_xor(s, o);
    out[(size_t)gw * 64 + lane] = acc - m - logf(s);
}

extern "C" void kernel_launch(void* const* d_in, const int* in_sizes, int n_in,
                              void* d_out, int out_size, void* d_ws, size_t ws_size,
                              hipStream_t stream) {
    const float* x    = (const float*)d_in[0];
    const int*   esrc = (const int*)d_in[1];
    const int*   edst = (const int*)d_in[2];
    const float* W1   = (const float*)d_in[3];
    const float* b1   = (const float*)d_in[4];
    const float* W2   = (const float*)d_in[5];
    const float* b2   = (const float*)d_in[6];

    const int N = in_sizes[0] / IN_DIM_C;
    const int E = in_sizes[1];

    // workspace carve (256B aligned chunks)
    char* p = (char*)d_ws;
    auto carve = [&](size_t bytes) -> char* {
        char* r = p; p += (bytes + 255) & ~(size_t)255; return r;
    };
    int*   deg    = (int*)carve((size_t)N * 4);
    int*   offs   = (int*)carve((size_t)(N + 1) * 4);
    int*   cursor = (int*)carve((size_t)N * 4);
    int*   part   = (int*)carve(512 * 4);
    float* dinv   = (float*)carve((size_t)N * 4);
    float* dinv2  = (float*)carve((size_t)N * 4);
    int*   csr    = (int*)carve((size_t)E * 4);
    float* bufA   = (float*)carve((size_t)N * HID_DIM_C * 4);
    float* bufB   = (float*)carve((size_t)N * HID_DIM_C * 4);

    const int NB = (N + 255) / 256;

    hipMemsetAsync(deg, 0, (size_t)N * 4, stream);
    k_deg  <<<(E + 255) / 256, 256, 0, stream>>>(edst, deg, E);
    k_scan1<<<NB, 256, 0, stream>>>(deg, offs, part, N);
    k_scan2<<<1, 512, 0, stream>>>(part, NB);
    k_scan3<<<NB, 256, 0, stream>>>(offs, cursor, part, N, E);
    k_fill <<<(E + 255) / 256, 256, 0, stream>>>(esrc, edst, cursor, csr, E);
    k_dinv <<<NB, 256, 0, stream>>>(deg, dinv, dinv2, N);

    const int aggBlocks = (N + 3) / 4;   // 4 waves (nodes) per 256-thread block
    // conv1 hop 1: x -> bufA (coeff 1)
    k_agg256<<<aggBlocks, 256, 0, stream>>>((const float4*)x, (float4*)bufA,
                                            offs, csr, dinv, 1.0f, N);
    // conv1 hop 2: bufA -> bufB (coeff e^-1)
    k_agg256<<<aggBlocks, 256, 0, stream>>>((const float4*)bufA, (float4*)bufB,
                                            offs, csr, dinv, EXP_NEG1, N);
    // h = selu(bufB @ W1 + b1) -> bufA
    dim3 g1((N + 63) / 64, HID_DIM_C / 64);
    k_gemm<<<g1, 256, 0, stream>>>(bufB, W1, b1, bufA, N, IN_DIM_C, HID_DIM_C, 1);
    // hw = bufA @ W2 (bias deferred) -> bufB
    dim3 g2((N + 63) / 64, OUT_DIM_C / 64);
    k_gemm<<<g2, 256, 0, stream>>>(bufA, W2, nullptr, bufB, N, HID_DIM_C, OUT_DIM_C, 0);
    // out = log_softmax(A2 @ hw + b2)
    k_agg64<<<aggBlocks, 256, 0, stream>>>(bufB, (float*)d_out, offs, csr, dinv2, b2, N);
}

// Round 4
// 1830.637 us; speedup vs baseline: 1.0896x; 1.0896x over previous
//
#include <hip/hip_runtime.h>
#include <math.h>

static constexpr int IN_DIM_C  = 256;
static constexpr int HID_DIM_C = 256;
static constexpr int OUT_DIM_C = 64;
static constexpr float EXP_NEG1   = 0.36787944117144233f;
static constexpr float SELU_ALPHA = 1.6732632423543772f;
static constexpr float SELU_SCALE = 1.0507009873554805f;

// ---------------- degree histogram ----------------
__global__ void k_deg(const int* __restrict__ dst, int* __restrict__ deg, int E) {
    int i = blockIdx.x * 256 + threadIdx.x;
    if (i < E) atomicAdd(&deg[dst[i]], 1);
}

// ---------------- hierarchical exclusive scan ----------------
__global__ void k_scan1(const int* __restrict__ deg, int* __restrict__ offs,
                        int* __restrict__ part, int N) {
    __shared__ int sm[256];
    int tid = threadIdx.x, idx = blockIdx.x * 256 + tid;
    int v = (idx < N) ? deg[idx] : 0;
    sm[tid] = v; __syncthreads();
    #pragma unroll
    for (int o = 1; o < 256; o <<= 1) {
        int t = (tid >= o) ? sm[tid - o] : 0;
        __syncthreads();
        sm[tid] += t;
        __syncthreads();
    }
    if (idx < N) offs[idx] = sm[tid] - v;          // exclusive
    if (tid == 255) part[blockIdx.x] = sm[255];    // block total
}

__global__ void k_scan2(int* __restrict__ part, int NB) {
    __shared__ int sm[512];
    int tid = threadIdx.x;
    int v = (tid < NB) ? part[tid] : 0;
    sm[tid] = v; __syncthreads();
    for (int o = 1; o < 512; o <<= 1) {
        int t = (tid >= o) ? sm[tid - o] : 0;
        __syncthreads();
        sm[tid] += t;
        __syncthreads();
    }
    if (tid < NB) part[tid] = sm[tid] - v;         // exclusive over partials
}

__global__ void k_scan3(int* __restrict__ offs, int* __restrict__ cursor,
                        const int* __restrict__ part, int N, int E) {
    int idx = blockIdx.x * 256 + threadIdx.x;
    if (idx < N) {
        int o = offs[idx] + part[idx >> 8];
        offs[idx] = o;
        cursor[idx] = o;
    }
    if (idx == 0) offs[N] = E;
}

// ---------------- CSR fill (incoming edges per dst) ----------------
__global__ void k_fill(const int* __restrict__ src, const int* __restrict__ dst,
                       int* __restrict__ cursor, int* __restrict__ csr, int E) {
    int i = blockIdx.x * 256 + threadIdx.x;
    if (i < E) {
        int d = dst[i];
        int slot = atomicAdd(&cursor[d], 1);
        csr[slot] = src[i];
    }
}

// ---------------- normalization coefficients ----------------
__global__ void k_dinv(const int* __restrict__ deg, float* __restrict__ dinv,
                       float* __restrict__ dinv2, int N) {
    int i = blockIdx.x * 256 + threadIdx.x;
    if (i < N) {
        int d = deg[i];
        dinv[i]  = (d > 0) ? rsqrtf((float)d) : 0.f;
        dinv2[i] = rsqrtf((float)(d + 1));
    }
}

// ---------------- 256-dim aggregation: one wave per node, 8-deep MLP ----------------
// out[node] = scl * dinv[node] * sum_e dinv[src_e] * x[src_e]
__global__ void k_agg256(const float4* __restrict__ xin, float4* __restrict__ yout,
                         const int* __restrict__ offs, const int* __restrict__ csr,
                         const float* __restrict__ dinv, float scl, int N) {
    int gw   = (blockIdx.x * blockDim.x + threadIdx.x) >> 6;  // node
    int lane = threadIdx.x & 63;
    if (gw >= N) return;
    int beg = offs[gw], end = offs[gw + 1];
    float ax = 0.f, ay = 0.f, az = 0.f, aw = 0.f;
    int e = beg;
    // 8-deep unrolled main loop: 8 index loads, then 8 weight loads + 8 row
    // gathers all in flight before any FMA (memory-level parallelism).
    for (; e + 8 <= end; e += 8) {
        int s[8];
        #pragma unroll
        for (int j = 0; j < 8; ++j) s[j] = csr[e + j];
        float w[8];
        #pragma unroll
        for (int j = 0; j < 8; ++j) w[j] = dinv[s[j]];
        float4 v[8];
        #pragma unroll
        for (int j = 0; j < 8; ++j) v[j] = xin[s[j] * 64 + lane];
        #pragma unroll
        for (int j = 0; j < 8; ++j) {
            ax = fmaf(w[j], v[j].x, ax); ay = fmaf(w[j], v[j].y, ay);
            az = fmaf(w[j], v[j].z, az); aw = fmaf(w[j], v[j].w, aw);
        }
    }
    for (; e < end; ++e) {
        int s = csr[e];
        float w = dinv[s];
        float4 v = xin[s * 64 + lane];
        ax = fmaf(w, v.x, ax); ay = fmaf(w, v.y, ay);
        az = fmaf(w, v.z, az); aw = fmaf(w, v.w, aw);
    }
    float c = scl * dinv[gw];
    float4 r; r.x = ax * c; r.y = ay * c; r.z = az * c; r.w = aw * c;
    yout[gw * 64 + lane] = r;
}

// ---------------- f32 tiled GEMM: C = A(MxK) * B(KxN) (+bias)(+selu) ----------------
__device__ __forceinline__ float selu_f(float v) {
    return v > 0.f ? SELU_SCALE * v : SELU_SCALE * SELU_ALPHA * expm1f(v);
}

__global__ __launch_bounds__(256) void k_gemm(
        const float* __restrict__ A, const float* __restrict__ B,
        const float* __restrict__ bias, float* __restrict__ C,
        int M, int K, int Ncols, int act) {
    __shared__ float As[16][65];
    __shared__ float Bs[16][64];
    int tid = threadIdx.x;
    int m0 = blockIdx.x * 64;
    int n0 = blockIdx.y * 64;
    int tx = tid & 15, ty = tid >> 4;
    int row0 = ty * 4, col0 = tx * 4;
    int la_r = tid >> 2;          // 0..63 (A row within tile)
    int la_k = (tid & 3) * 4;     // 0,4,8,12
    int lb_k = tid >> 4;          // 0..15
    int lb_n = (tid & 15) * 4;
    float acc[4][4] = {};
    for (int k0 = 0; k0 < K; k0 += 16) {
        float4 av;
        int arow = m0 + la_r;
        if (arow < M) av = *(const float4*)&A[(size_t)arow * K + k0 + la_k];
        else          av = make_float4(0.f, 0.f, 0.f, 0.f);
        float4 bv = *(const float4*)&B[(size_t)(k0 + lb_k) * Ncols + n0 + lb_n];
        __syncthreads();
        As[la_k + 0][la_r] = av.x; As[la_k + 1][la_r] = av.y;
        As[la_k + 2][la_r] = av.z; As[la_k + 3][la_r] = av.w;
        *(float4*)&Bs[lb_k][lb_n] = bv;
        __syncthreads();
        #pragma unroll
        for (int kk = 0; kk < 16; ++kk) {
            float a0 = As[kk][row0 + 0], a1 = As[kk][row0 + 1];
            float a2 = As[kk][row0 + 2], a3 = As[kk][row0 + 3];
            float4 b = *(float4*)&Bs[kk][col0];
            acc[0][0] = fmaf(a0, b.x, acc[0][0]); acc[0][1] = fmaf(a0, b.y, acc[0][1]);
            acc[0][2] = fmaf(a0, b.z, acc[0][2]); acc[0][3] = fmaf(a0, b.w, acc[0][3]);
            acc[1][0] = fmaf(a1, b.x, acc[1][0]); acc[1][1] = fmaf(a1, b.y, acc[1][1]);
            acc[1][2] = fmaf(a1, b.z, acc[1][2]); acc[1][3] = fmaf(a1, b.w, acc[1][3]);
            acc[2][0] = fmaf(a2, b.x, acc[2][0]); acc[2][1] = fmaf(a2, b.y, acc[2][1]);
            acc[2][2] = fmaf(a2, b.z, acc[2][2]); acc[2][3] = fmaf(a2, b.w, acc[2][3]);
            acc[3][0] = fmaf(a3, b.x, acc[3][0]); acc[3][1] = fmaf(a3, b.y, acc[3][1]);
            acc[3][2] = fmaf(a3, b.z, acc[3][2]); acc[3][3] = fmaf(a3, b.w, acc[3][3]);
        }
    }
    #pragma unroll
    for (int i = 0; i < 4; ++i) {
        int row = m0 + row0 + i;
        if (row < M) {
            float4 o;
            o.x = acc[i][0]; o.y = acc[i][1]; o.z = acc[i][2]; o.w = acc[i][3];
            if (bias) {
                o.x += bias[n0 + col0 + 0]; o.y += bias[n0 + col0 + 1];
                o.z += bias[n0 + col0 + 2]; o.w += bias[n0 + col0 + 3];
            }
            if (act) { o.x = selu_f(o.x); o.y = selu_f(o.y); o.z = selu_f(o.z); o.w = selu_f(o.w); }
            *(float4*)&C[(size_t)row * Ncols + n0 + col0] = o;
        }
    }
}

// ---------------- final: 64-dim agg (self loop) + bias + log_softmax, 8-deep MLP ----------------
__global__ void k_agg64(const float* __restrict__ hw, float* __restrict__ out,
                        const int* __restrict__ offs, const int* __restrict__ csr,
                        const float* __restrict__ dinv2, const float* __restrict__ b2, int N) {
    int gw   = (blockIdx.x * blockDim.x + threadIdx.x) >> 6;
    int lane = threadIdx.x & 63;
    if (gw >= N) return;
    int beg = offs[gw], end = offs[gw + 1];
    float di = dinv2[gw];
    // out = di * ( di*h_self + sum_e dinv2[s]*h_s )  + b2, then log_softmax
    float acc = di * hw[(size_t)gw * 64 + lane];      // self loop (di^2 after final *di)
    int e = beg;
    for (; e + 8 <= end; e += 8) {
        int s[8];
        #pragma unroll
        for (int j = 0; j < 8; ++j) s[j] = csr[e + j];
        float w[8];
        #pragma unroll
        for (int j = 0; j < 8; ++j) w[j] = dinv2[s[j]];
        float v[8];
        #pragma unroll
        for (int j = 0; j < 8; ++j) v[j] = hw[(size_t)s[j] * 64 + lane];
        #pragma unroll
        for (int j = 0; j < 8; ++j) acc = fmaf(w[j], v[j], acc);
    }
    for (; e < end; ++e) {
        int s = csr[e];
        acc = fmaf(dinv2[s], hw[(size_t)s * 64 + lane], acc);
    }
    acc = di * acc;
    acc += b2[lane];
    // log_softmax across the 64 lanes (= the 64 output classes)
    float m = acc;
    #pragma unroll
    for (int o = 32; o > 0; o >>= 1) m = fmaxf(m, __shfl_xor(m, o));
    float ex = expf(acc - m);
    float s = ex;
    #pragma unroll
    for (int o = 32; o > 0; o >>= 1) s += __shfl_xor(s, o);
    out[(size_t)gw * 64 + lane] = acc - m - logf(s);
}

extern "C" void kernel_launch(void* const* d_in, const int* in_sizes, int n_in,
                              void* d_out, int out_size, void* d_ws, size_t ws_size,
                              hipStream_t stream) {
    const float* x    = (const float*)d_in[0];
    const int*   esrc = (const int*)d_in[1];
    const int*   edst = (const int*)d_in[2];
    const float* W1   = (const float*)d_in[3];
    const float* b1   = (const float*)d_in[4];
    const float* W2   = (const float*)d_in[5];
    const float* b2   = (const float*)d_in[6];

    const int N = in_sizes[0] / IN_DIM_C;
    const int E = in_sizes[1];

    // workspace carve (256B aligned chunks)
    char* p = (char*)d_ws;
    auto carve = [&](size_t bytes) -> char* {
        char* r = p; p += (bytes + 255) & ~(size_t)255; return r;
    };
    int*   deg    = (int*)carve((size_t)N * 4);
    int*   offs   = (int*)carve((size_t)(N + 1) * 4);
    int*   cursor = (int*)carve((size_t)N * 4);
    int*   part   = (int*)carve(512 * 4);
    float* dinv   = (float*)carve((size_t)N * 4);
    float* dinv2  = (float*)carve((size_t)N * 4);
    int*   csr    = (int*)carve((size_t)E * 4);
    float* bufA   = (float*)carve((size_t)N * HID_DIM_C * 4);
    float* bufB   = (float*)carve((size_t)N * HID_DIM_C * 4);

    const int NB = (N + 255) / 256;

    hipMemsetAsync(deg, 0, (size_t)N * 4, stream);
    k_deg  <<<(E + 255) / 256, 256, 0, stream>>>(edst, deg, E);
    k_scan1<<<NB, 256, 0, stream>>>(deg, offs, part, N);
    k_scan2<<<1, 512, 0, stream>>>(part, NB);
    k_scan3<<<NB, 256, 0, stream>>>(offs, cursor, part, N, E);
    k_fill <<<(E + 255) / 256, 256, 0, stream>>>(esrc, edst, cursor, csr, E);
    k_dinv <<<NB, 256, 0, stream>>>(deg, dinv, dinv2, N);

    const int aggBlocks = (N + 3) / 4;   // 4 waves (nodes) per 256-thread block
    // conv1 hop 1: x -> bufA (coeff 1)
    k_agg256<<<aggBlocks, 256, 0, stream>>>((const float4*)x, (float4*)bufA,
                                            offs, csr, dinv, 1.0f, N);
    // conv1 hop 2: bufA -> bufB (coeff e^-1)
    k_agg256<<<aggBlocks, 256, 0, stream>>>((const float4*)bufA, (float4*)bufB,
                                            offs, csr, dinv, EXP_NEG1, N);
    // h = selu(bufB @ W1 + b1) -> bufA
    dim3 g1((N + 63) / 64, HID_DIM_C / 64);
    k_gemm<<<g1, 256, 0, stream>>>(bufB, W1, b1, bufA, N, IN_DIM_C, HID_DIM_C, 1);
    // hw = bufA @ W2 (bias deferred) -> bufB
    dim3 g2((N + 63) / 64, OUT_DIM_C / 64);
    k_gemm<<<g2, 256, 0, stream>>>(bufA, W2, nullptr, bufB, N, HID_DIM_C, OUT_DIM_C, 0);
    // out = log_softmax(A2 @ hw + b2)
    k_agg64<<<aggBlocks, 256, 0, stream>>>(bufB, (float*)d_out, offs, csr, dinv2, b2, N);
}

// Round 6
// 1185.195 us; speedup vs baseline: 1.6830x; 1.5446x over previous
//
#include <hip/hip_runtime.h>
#include <math.h>

static constexpr int IN_DIM_C  = 256;
static constexpr int HID_DIM_C = 256;
static constexpr int OUT_DIM_C = 64;
static constexpr float EXP_NEG1   = 0.36787944117144233f;
static constexpr float SELU_ALPHA = 1.6732632423543772f;
static constexpr float SELU_SCALE = 1.0507009873554805f;

typedef __attribute__((ext_vector_type(4))) float f32x4;
typedef __attribute__((ext_vector_type(8))) short bf16x8;

// ---- bf16 helpers (RNE) ----
__device__ __forceinline__ unsigned short bf1(float f) {
    unsigned int u = __float_as_uint(f);
    u = u + 0x7FFFu + ((u >> 16) & 1u);
    return (unsigned short)(u >> 16);
}
__device__ __forceinline__ unsigned int bfpack2(float lo, float hi) {
    return (unsigned int)bf1(lo) | ((unsigned int)bf1(hi) << 16);
}
__device__ __forceinline__ float fb(unsigned short h) {
    return __uint_as_float(((unsigned int)h) << 16);
}

// ---------------- degree histogram ----------------
__global__ void k_deg(const int* __restrict__ dst, int* __restrict__ deg, int E) {
    int i = blockIdx.x * 256 + threadIdx.x;
    if (i < E) atomicAdd(&deg[dst[i]], 1);
}

// ---------------- hierarchical exclusive scan ----------------
__global__ void k_scan1(const int* __restrict__ deg, int* __restrict__ offs,
                        int* __restrict__ part, int N) {
    __shared__ int sm[256];
    int tid = threadIdx.x, idx = blockIdx.x * 256 + tid;
    int v = (idx < N) ? deg[idx] : 0;
    sm[tid] = v; __syncthreads();
    #pragma unroll
    for (int o = 1; o < 256; o <<= 1) {
        int t = (tid >= o) ? sm[tid - o] : 0;
        __syncthreads();
        sm[tid] += t;
        __syncthreads();
    }
    if (idx < N) offs[idx] = sm[tid] - v;
    if (tid == 255) part[blockIdx.x] = sm[255];
}

__global__ void k_scan2(int* __restrict__ part, int NB) {
    __shared__ int sm[512];
    int tid = threadIdx.x;
    int v = (tid < NB) ? part[tid] : 0;
    sm[tid] = v; __syncthreads();
    for (int o = 1; o < 512; o <<= 1) {
        int t = (tid >= o) ? sm[tid - o] : 0;
        __syncthreads();
        sm[tid] += t;
        __syncthreads();
    }
    if (tid < NB) part[tid] = sm[tid] - v;
}

__global__ void k_scan3(int* __restrict__ offs, int* __restrict__ cursor,
                        const int* __restrict__ part, int N, int E) {
    int idx = blockIdx.x * 256 + threadIdx.x;
    if (idx < N) {
        int o = offs[idx] + part[idx >> 8];
        offs[idx] = o;
        cursor[idx] = o;
    }
    if (idx == 0) offs[N] = E;
}

// ---------------- CSR fill ----------------
__global__ void k_fill(const int* __restrict__ src, const int* __restrict__ dst,
                       int* __restrict__ cursor, int* __restrict__ csr, int E) {
    int i = blockIdx.x * 256 + threadIdx.x;
    if (i < E) {
        int d = dst[i];
        int slot = atomicAdd(&cursor[d], 1);
        csr[slot] = src[i];
    }
}

// ---------------- normalization coefficients ----------------
__global__ void k_dinv(const int* __restrict__ deg, float* __restrict__ dinv,
                       float* __restrict__ dinv2, int N) {
    int i = blockIdx.x * 256 + threadIdx.x;
    if (i < N) {
        int d = deg[i];
        dinv[i]  = (d > 0) ? rsqrtf((float)d) : 0.f;
        dinv2[i] = rsqrtf((float)(d + 1));
    }
}

// ---------------- f32 -> bf16 elementwise (float4 -> 4 bf16) ----------------
__global__ void k_cvt(const float4* __restrict__ in, uint2* __restrict__ out, int n4) {
    int i = blockIdx.x * 256 + threadIdx.x;
    if (i < n4) {
        float4 v = in[i];
        uint2 o;
        o.x = bfpack2(v.x, v.y);
        o.y = bfpack2(v.z, v.w);
        out[i] = o;
    }
}

// ---------------- pack W[K][N] f32 -> MFMA B-fragment layout, bf16 ----------------
// Bp[((t*KC + c)*64 + l)*8 + j] = bf16( W[c*32 + (l>>4)*8 + j][t*16 + (l&15)] )
__global__ void k_packB(const float* __restrict__ W, unsigned short* __restrict__ Bp,
                        int K, int N) {
    int idx = blockIdx.x * 256 + threadIdx.x;
    if (idx >= K * N) return;
    int j = idx & 7;
    int l = (idx >> 3) & 63;
    int rest = idx >> 9;
    int KC = K >> 5;
    int c = rest % KC, t = rest / KC;
    int k = c * 32 + ((l >> 4) << 3) + j;
    int n = t * 16 + (l & 15);
    Bp[idx] = bf1(W[(size_t)k * N + n]);
}

// ---------------- 256-dim aggregation on bf16 rows (512B/row) ----------------
// out[node] = bf16( scl * dinv[node] * sum_e dinv[src]*x[src] )
__global__ void k_aggbf(const uint2* __restrict__ xin, uint2* __restrict__ yout,
                        const int* __restrict__ offs, const int* __restrict__ csr,
                        const float* __restrict__ dinv, float scl, int N) {
    int gw   = (blockIdx.x * blockDim.x + threadIdx.x) >> 6;
    int lane = threadIdx.x & 63;
    if (gw >= N) return;
    int beg = offs[gw], end = offs[gw + 1];
    float a0 = 0.f, a1 = 0.f, a2 = 0.f, a3 = 0.f;
    int e = beg;
    for (; e + 8 <= end; e += 8) {
        int s[8];
        #pragma unroll
        for (int j = 0; j < 8; ++j) s[j] = csr[e + j];
        float w[8];
        #pragma unroll
        for (int j = 0; j < 8; ++j) w[j] = dinv[s[j]];
        uint2 v[8];
        #pragma unroll
        for (int j = 0; j < 8; ++j) v[j] = xin[(size_t)s[j] * 64 + lane];
        #pragma unroll
        for (int j = 0; j < 8; ++j) {
            a0 = fmaf(w[j], __uint_as_float(v[j].x << 16), a0);
            a1 = fmaf(w[j], __uint_as_float(v[j].x & 0xFFFF0000u), a1);
            a2 = fmaf(w[j], __uint_as_float(v[j].y << 16), a2);
            a3 = fmaf(w[j], __uint_as_float(v[j].y & 0xFFFF0000u), a3);
        }
    }
    for (; e < end; ++e) {
        int s = csr[e];
        float w = dinv[s];
        uint2 v = xin[(size_t)s * 64 + lane];
        a0 = fmaf(w, __uint_as_float(v.x << 16), a0);
        a1 = fmaf(w, __uint_as_float(v.x & 0xFFFF0000u), a1);
        a2 = fmaf(w, __uint_as_float(v.y << 16), a2);
        a3 = fmaf(w, __uint_as_float(v.y & 0xFFFF0000u), a3);
    }
    float c = scl * dinv[gw];
    uint2 r;
    r.x = bfpack2(a0 * c, a1 * c);
    r.y = bfpack2(a2 * c, a3 * c);
    yout[(size_t)gw * 64 + lane] = r;
}

// ---------------- bf16 MFMA GEMM: C[M][N] = A[M][K] * Bp + bias, optional selu ----------------
__device__ __forceinline__ float selu_f(float v) {
    return v > 0.f ? SELU_SCALE * v : SELU_SCALE * SELU_ALPHA * expm1f(v);
}

template <int K>
__global__ __launch_bounds__(256) void k_mgemm(
        const unsigned short* __restrict__ A,   // [M][K] bf16 row-major
        const unsigned short* __restrict__ Bp,  // packed fragments
        const float* __restrict__ bias,         // [N] f32 or null
        unsigned short* __restrict__ Cb,        // [M][N] bf16 out
        int M, int Ncols, int act) {
    constexpr int KC = K >> 5;                  // 32-wide k-chunks
    int wid  = threadIdx.x >> 6;                // wave 0..3
    int lane = threadIdx.x & 63;
    int m0   = blockIdx.x * 64 + wid * 16;      // this wave's 16 rows
    int arow = m0 + (lane & 15);
    int kg   = lane >> 4;                       // k-group 0..3
    bf16x8 af[KC];
    bf16x8 zf = {0, 0, 0, 0, 0, 0, 0, 0};
    bool valid = arow < M;
    #pragma unroll
    for (int c = 0; c < KC; ++c) {
        if (valid) af[c] = *(const bf16x8*)&A[(size_t)arow * K + c * 32 + kg * 8];
        else       af[c] = zf;
    }
    int NT = Ncols >> 4;
    for (int t = 0; t < NT; ++t) {
        f32x4 acc = {0.f, 0.f, 0.f, 0.f};
        #pragma unroll
        for (int c = 0; c < KC; ++c) {
            bf16x8 bfv = *(const bf16x8*)&Bp[(((size_t)t * KC + c) * 64 + lane) * 8];
            acc = __builtin_amdgcn_mfma_f32_16x16x32_bf16(af[c], bfv, acc, 0, 0, 0);
        }
        int n = t * 16 + (lane & 15);
        float bv = bias ? bias[n] : 0.f;
        #pragma unroll
        for (int r = 0; r < 4; ++r) {
            int m = m0 + (lane >> 4) * 4 + r;
            if (m < M) {
                float v = acc[r] + bv;
                if (act) v = selu_f(v);
                Cb[(size_t)m * Ncols + n] = bf1(v);
            }
        }
    }
}

// ---------------- final: 64-dim bf16 agg (self loop) + bias + log_softmax ----------------
__global__ void k_agg64(const unsigned short* __restrict__ hw, float* __restrict__ out,
                        const int* __restrict__ offs, const int* __restrict__ csr,
                        const float* __restrict__ dinv2, const float* __restrict__ b2, int N) {
    int gw   = (blockIdx.x * blockDim.x + threadIdx.x) >> 6;
    int lane = threadIdx.x & 63;
    if (gw >= N) return;
    int beg = offs[gw], end = offs[gw + 1];
    float di = dinv2[gw];
    float acc = di * fb(hw[(size_t)gw * 64 + lane]);   // self loop (di^2 after final *di)
    int e = beg;
    for (; e + 8 <= end; e += 8) {
        int s[8];
        #pragma unroll
        for (int j = 0; j < 8; ++j) s[j] = csr[e + j];
        float w[8];
        #pragma unroll
        for (int j = 0; j < 8; ++j) w[j] = dinv2[s[j]];
        unsigned short v[8];
        #pragma unroll
        for (int j = 0; j < 8; ++j) v[j] = hw[(size_t)s[j] * 64 + lane];
        #pragma unroll
        for (int j = 0; j < 8; ++j) acc = fmaf(w[j], fb(v[j]), acc);
    }
    for (; e < end; ++e) {
        int s = csr[e];
        acc = fmaf(dinv2[s], fb(hw[(size_t)s * 64 + lane]), acc);
    }
    acc = di * acc + b2[lane];
    float m = acc;
    #pragma unroll
    for (int o = 32; o > 0; o >>= 1) m = fmaxf(m, __shfl_xor(m, o));
    float ex = expf(acc - m);
    float s = ex;
    #pragma unroll
    for (int o = 32; o > 0; o >>= 1) s += __shfl_xor(s, o);
    out[(size_t)gw * 64 + lane] = acc - m - logf(s);
}

extern "C" void kernel_launch(void* const* d_in, const int* in_sizes, int n_in,
                              void* d_out, int out_size, void* d_ws, size_t ws_size,
                              hipStream_t stream) {
    const float* x    = (const float*)d_in[0];
    const int*   esrc = (const int*)d_in[1];
    const int*   edst = (const int*)d_in[2];
    const float* W1   = (const float*)d_in[3];
    const float* b1   = (const float*)d_in[4];
    const float* W2   = (const float*)d_in[5];
    const float* b2   = (const float*)d_in[6];

    const int N = in_sizes[0] / IN_DIM_C;
    const int E = in_sizes[1];

    char* p = (char*)d_ws;
    auto carve = [&](size_t bytes) -> char* {
        char* r = p; p += (bytes + 255) & ~(size_t)255; return r;
    };
    int*   deg    = (int*)carve((size_t)N * 4);
    int*   offs   = (int*)carve((size_t)(N + 1) * 4);
    int*   cursor = (int*)carve((size_t)N * 4);
    int*   part   = (int*)carve(512 * 4);
    float* dinv   = (float*)carve((size_t)N * 4);
    float* dinv2  = (float*)carve((size_t)N * 4);
    int*   csr    = (int*)carve((size_t)E * 4);
    // three bf16 node buffers, 51.2MB each, with reuse:
    unsigned short* buf0 = (unsigned short*)carve((size_t)N * 256 * 2); // xbf -> later h
    unsigned short* buf1 = (unsigned short*)carve((size_t)N * 256 * 2); // h1  -> later hw
    unsigned short* buf2 = (unsigned short*)carve((size_t)N * 256 * 2); // h2
    unsigned short* W1p  = (unsigned short*)carve((size_t)IN_DIM_C * HID_DIM_C * 2);
    unsigned short* W2p  = (unsigned short*)carve((size_t)HID_DIM_C * OUT_DIM_C * 2);

    const int NB = (N + 255) / 256;

    hipMemsetAsync(deg, 0, (size_t)N * 4, stream);
    k_deg  <<<(E + 255) / 256, 256, 0, stream>>>(edst, deg, E);
    k_scan1<<<NB, 256, 0, stream>>>(deg, offs, part, N);
    k_scan2<<<1, 512, 0, stream>>>(part, NB);
    k_scan3<<<NB, 256, 0, stream>>>(offs, cursor, part, N, E);
    k_fill <<<(E + 255) / 256, 256, 0, stream>>>(esrc, edst, cursor, csr, E);
    k_dinv <<<NB, 256, 0, stream>>>(deg, dinv, dinv2, N);

    // x -> bf16
    int n4 = N * IN_DIM_C / 4;
    k_cvt<<<(n4 + 255) / 256, 256, 0, stream>>>((const float4*)x, (uint2*)buf0, n4);
    // pack weights into MFMA B-fragment layout
    k_packB<<<(IN_DIM_C * HID_DIM_C + 255) / 256, 256, 0, stream>>>(W1, W1p, IN_DIM_C, HID_DIM_C);
    k_packB<<<(HID_DIM_C * OUT_DIM_C + 255) / 256, 256, 0, stream>>>(W2, W2p, HID_DIM_C, OUT_DIM_C);

    const int aggBlocks = (N + 3) / 4;     // 4 waves (nodes) per 256-thread block
    // conv1 hop 1: xbf(buf0) -> h1(buf1)
    k_aggbf<<<aggBlocks, 256, 0, stream>>>((const uint2*)buf0, (uint2*)buf1,
                                           offs, csr, dinv, 1.0f, N);
    // conv1 hop 2: h1(buf1) -> h2(buf2), coeff e^-1
    k_aggbf<<<aggBlocks, 256, 0, stream>>>((const uint2*)buf1, (uint2*)buf2,
                                           offs, csr, dinv, EXP_NEG1, N);
    // h = selu(h2 @ W1 + b1) -> buf0 (xbf dead)
    k_mgemm<256><<<(N + 63) / 64, 256, 0, stream>>>(buf2, W1p, b1, buf0, N, HID_DIM_C, 1);
    // hw = h @ W2 (bias deferred) -> buf1 (h1 dead)
    k_mgemm<256><<<(N + 63) / 64, 256, 0, stream>>>(buf0, W2p, nullptr, buf1, N, OUT_DIM_C, 0);
    // out = log_softmax(A2 @ hw + b2)
    k_agg64<<<aggBlocks, 256, 0, stream>>>(buf1, (float*)d_out, offs, csr, dinv2, b2, N);
}

// Round 11
// 910.825 us; speedup vs baseline: 2.1900x; 1.3012x over previous
//
#include <hip/hip_runtime.h>
#include <math.h>

static constexpr int IN_DIM_C  = 256;
static constexpr int HID_DIM_C = 256;
static constexpr int OUT_DIM_C = 64;
static constexpr float EXP_NEG1   = 0.36787944117144233f;
static constexpr float SELU_ALPHA = 1.6732632423543772f;
static constexpr float SELU_SCALE = 1.0507009873554805f;

// bucket sort params: bucket = dst >> BSH (512 nodes per bucket)
static constexpr int NBLK  = 256;   // sort blocks
static constexpr int NBUCK = 256;   // buckets
static constexpr int BSH   = 9;     // log2(nodes per bucket)
static constexpr int BMASK = (1 << BSH) - 1;

typedef __attribute__((ext_vector_type(4))) float f32x4;
typedef __attribute__((ext_vector_type(8))) short bf16x8;

// ---- bf16 helpers (RNE) ----
__device__ __forceinline__ unsigned short bf1(float f) {
    unsigned int u = __float_as_uint(f);
    u = u + 0x7FFFu + ((u >> 16) & 1u);
    return (unsigned short)(u >> 16);
}
__device__ __forceinline__ unsigned int bfpack2(float lo, float hi) {
    return (unsigned int)bf1(lo) | ((unsigned int)bf1(hi) << 16);
}
__device__ __forceinline__ float fb(unsigned short h) {
    return __uint_as_float(((unsigned int)h) << 16);
}

// ---------------- pass 1: per-block bucket histogram ----------------
// counts[bucket][block] (bucket-major for the scan)
__global__ __launch_bounds__(256) void k_hist(const int* __restrict__ dst,
                                              int* __restrict__ counts, int E) {
    __shared__ int hist[NBUCK];
    int tid = threadIdx.x, blk = blockIdx.x;
    hist[tid] = 0;
    __syncthreads();
    int ch = (E + NBLK - 1) / NBLK;
    int beg = blk * ch, end = min(beg + ch, E);
    for (int i = beg + tid; i < end; i += 256)
        atomicAdd(&hist[dst[i] >> BSH], 1);
    __syncthreads();
    counts[tid * NBLK + blk] = hist[tid];
}

// ---------------- hierarchical exclusive scan (generic) ----------------
__global__ void k_scan1(const int* __restrict__ in, int* __restrict__ out,
                        int* __restrict__ part, int n) {
    __shared__ int sm[256];
    int tid = threadIdx.x, idx = blockIdx.x * 256 + tid;
    int v = (idx < n) ? in[idx] : 0;
    sm[tid] = v; __syncthreads();
    #pragma unroll
    for (int o = 1; o < 256; o <<= 1) {
        int t = (tid >= o) ? sm[tid - o] : 0;
        __syncthreads();
        sm[tid] += t;
        __syncthreads();
    }
    if (idx < n) out[idx] = sm[tid] - v;
    if (tid == 255) part[blockIdx.x] = sm[255];
}

__global__ void k_scan2(int* __restrict__ part, int NB) {
    __shared__ int sm[512];
    int tid = threadIdx.x;
    int v = (tid < NB) ? part[tid] : 0;
    sm[tid] = v; __syncthreads();
    for (int o = 1; o < 512; o <<= 1) {
        int t = (tid >= o) ? sm[tid - o] : 0;
        __syncthreads();
        sm[tid] += t;
        __syncthreads();
    }
    if (tid < NB) part[tid] = sm[tid] - v;
}

__global__ void k_scan3b(int* __restrict__ v, const int* __restrict__ part, int n) {
    int idx = blockIdx.x * 256 + threadIdx.x;
    if (idx < n) v[idx] += part[idx >> 8];
}

// ---------------- pass 2: scatter edges into bucket-sorted packed array ----------------
// spk[slot] = (src << BSH) | (dst & BMASK); slots from per-(bucket,block) bases.
__global__ __launch_bounds__(256) void k_scat(const int* __restrict__ src,
                                              const int* __restrict__ dst,
                                              const int* __restrict__ sc,
                                              unsigned int* __restrict__ spk, int E) {
    __shared__ int cur[NBUCK];
    int tid = threadIdx.x, blk = blockIdx.x;
    cur[tid] = sc[tid * NBLK + blk];
    __syncthreads();
    int ch = (E + NBLK - 1) / NBLK;
    int beg = blk * ch, end = min(beg + ch, E);
    for (int i = beg + tid; i < end; i += 256) {
        int d = dst[i];
        int b = d >> BSH;
        int slot = atomicAdd(&cur[b], 1);
        spk[slot] = ((unsigned int)src[i] << BSH) | (unsigned int)(d & BMASK);
    }
}

// ---------------- pass 3: per-bucket CSR finalize (one block per bucket) ----------------
// Produces csr (contiguous writes), offs[node], deg[node].
__global__ __launch_bounds__(256) void k_csr(const unsigned int* __restrict__ spk,
                                             const int* __restrict__ sc,
                                             int* __restrict__ csr,
                                             int* __restrict__ offsG,
                                             int* __restrict__ degG, int N, int E) {
    __shared__ int ldeg[512], loffs[512], sm[256];
    int tid = threadIdx.x, b = blockIdx.x;
    int start = sc[b * NBLK];
    int end   = (b == NBUCK - 1) ? E : sc[(b + 1) * NBLK];
    ldeg[tid] = 0; ldeg[tid + 256] = 0;
    __syncthreads();
    for (int i = start + tid; i < end; i += 256)
        atomicAdd(&ldeg[spk[i] & BMASK], 1);
    __syncthreads();
    int d0 = ldeg[2 * tid], d1 = ldeg[2 * tid + 1];
    int s = d0 + d1;
    sm[tid] = s; __syncthreads();
    #pragma unroll
    for (int o = 1; o < 256; o <<= 1) {
        int t = (tid >= o) ? sm[tid - o] : 0;
        __syncthreads();
        sm[tid] += t;
        __syncthreads();
    }
    int excl = sm[tid] - s;
    loffs[2 * tid] = excl;
    loffs[2 * tid + 1] = excl + d0;
    int node0 = b << BSH;
    int n0 = node0 + 2 * tid, n1 = n0 + 1;
    if (n0 < N) { offsG[n0] = start + excl;      degG[n0] = d0; }
    if (n1 < N) { offsG[n1] = start + excl + d0; degG[n1] = d1; }
    if (b == NBUCK - 1 && tid == 0) offsG[N] = E;
    __syncthreads();
    ldeg[tid] = 0; ldeg[tid + 256] = 0;   // reuse as per-node cursors
    __syncthreads();
    for (int i = start + tid; i < end; i += 256) {
        unsigned int pk = spk[i];
        int n = pk & BMASK;
        int k = atomicAdd(&ldeg[n], 1);
        csr[start + loffs[n] + k] = (int)(pk >> BSH);
    }
}

// ---------------- normalization coefficients ----------------
__global__ void k_dinv(const int* __restrict__ deg, float* __restrict__ dinv,
                       float* __restrict__ dinv2, int N) {
    int i = blockIdx.x * 256 + threadIdx.x;
    if (i < N) {
        int d = deg[i];
        dinv[i]  = (d > 0) ? rsqrtf((float)d) : 0.f;
        dinv2[i] = rsqrtf((float)(d + 1));
    }
}

// ---------------- f32 -> bf16 elementwise (float4 -> 4 bf16) ----------------
__global__ void k_cvt(const float4* __restrict__ in, uint2* __restrict__ out, int n4) {
    int i = blockIdx.x * 256 + threadIdx.x;
    if (i < n4) {
        float4 v = in[i];
        uint2 o;
        o.x = bfpack2(v.x, v.y);
        o.y = bfpack2(v.z, v.w);
        out[i] = o;
    }
}

// ---------------- pack W[K][N] f32 -> MFMA B-fragment layout, bf16 ----------------
__global__ void k_packB(const float* __restrict__ W, unsigned short* __restrict__ Bp,
                        int K, int N) {
    int idx = blockIdx.x * 256 + threadIdx.x;
    if (idx >= K * N) return;
    int j = idx & 7;
    int l = (idx >> 3) & 63;
    int rest = idx >> 9;
    int KC = K >> 5;
    int c = rest % KC, t = rest / KC;
    int k = c * 32 + ((l >> 4) << 3) + j;
    int n = t * 16 + (l & 15);
    Bp[idx] = bf1(W[(size_t)k * N + n]);
}

// ---------------- 256-dim aggregation on bf16 rows (512B/row) ----------------
__global__ void k_aggbf(const uint2* __restrict__ xin, uint2* __restrict__ yout,
                        const int* __restrict__ offs, const int* __restrict__ csr,
                        const float* __restrict__ dinv, float scl, int N) {
    int gw   = (blockIdx.x * blockDim.x + threadIdx.x) >> 6;
    int lane = threadIdx.x & 63;
    if (gw >= N) return;
    int beg = offs[gw], end = offs[gw + 1];
    float a0 = 0.f, a1 = 0.f, a2 = 0.f, a3 = 0.f;
    int e = beg;
    for (; e + 8 <= end; e += 8) {
        int s[8];
        #pragma unroll
        for (int j = 0; j < 8; ++j) s[j] = csr[e + j];
        float w[8];
        #pragma unroll
        for (int j = 0; j < 8; ++j) w[j] = dinv[s[j]];
        uint2 v[8];
        #pragma unroll
        for (int j = 0; j < 8; ++j) v[j] = xin[(size_t)s[j] * 64 + lane];
        #pragma unroll
        for (int j = 0; j < 8; ++j) {
            a0 = fmaf(w[j], __uint_as_float(v[j].x << 16), a0);
            a1 = fmaf(w[j], __uint_as_float(v[j].x & 0xFFFF0000u), a1);
            a2 = fmaf(w[j], __uint_as_float(v[j].y << 16), a2);
            a3 = fmaf(w[j], __uint_as_float(v[j].y & 0xFFFF0000u), a3);
        }
    }
    for (; e < end; ++e) {
        int s = csr[e];
        float w = dinv[s];
        uint2 v = xin[(size_t)s * 64 + lane];
        a0 = fmaf(w, __uint_as_float(v.x << 16), a0);
        a1 = fmaf(w, __uint_as_float(v.x & 0xFFFF0000u), a1);
        a2 = fmaf(w, __uint_as_float(v.y << 16), a2);
        a3 = fmaf(w, __uint_as_float(v.y & 0xFFFF0000u), a3);
    }
    float c = scl * dinv[gw];
    uint2 r;
    r.x = bfpack2(a0 * c, a1 * c);
    r.y = bfpack2(a2 * c, a3 * c);
    yout[(size_t)gw * 64 + lane] = r;
}

// ---------------- bf16 MFMA GEMM ----------------
__device__ __forceinline__ float selu_f(float v) {
    return v > 0.f ? SELU_SCALE * v : SELU_SCALE * SELU_ALPHA * expm1f(v);
}

template <int K>
__global__ __launch_bounds__(256) void k_mgemm(
        const unsigned short* __restrict__ A,   // [M][K] bf16 row-major
        const unsigned short* __restrict__ Bp,  // packed fragments
        const float* __restrict__ bias,
        unsigned short* __restrict__ Cb,        // [M][N] bf16 out
        int M, int Ncols, int act) {
    constexpr int KC = K >> 5;
    int wid  = threadIdx.x >> 6;
    int lane = threadIdx.x & 63;
    int m0   = blockIdx.x * 64 + wid * 16;
    int arow = m0 + (lane & 15);
    int kg   = lane >> 4;
    bf16x8 af[KC];
    bf16x8 zf = {0, 0, 0, 0, 0, 0, 0, 0};
    bool valid = arow < M;
    #pragma unroll
    for (int c = 0; c < KC; ++c) {
        if (valid) af[c] = *(const bf16x8*)&A[(size_t)arow * K + c * 32 + kg * 8];
        else       af[c] = zf;
    }
    int NT = Ncols >> 4;
    for (int t = 0; t < NT; ++t) {
        f32x4 acc = {0.f, 0.f, 0.f, 0.f};
        #pragma unroll
        for (int c = 0; c < KC; ++c) {
            bf16x8 bfv = *(const bf16x8*)&Bp[(((size_t)t * KC + c) * 64 + lane) * 8];
            acc = __builtin_amdgcn_mfma_f32_16x16x32_bf16(af[c], bfv, acc, 0, 0, 0);
        }
        int n = t * 16 + (lane & 15);
        float bv = bias ? bias[n] : 0.f;
        #pragma unroll
        for (int r = 0; r < 4; ++r) {
            int m = m0 + (lane >> 4) * 4 + r;
            if (m < M) {
                float v = acc[r] + bv;
                if (act) v = selu_f(v);
                Cb[(size_t)m * Ncols + n] = bf1(v);
            }
        }
    }
}

// ---------------- final: 64-dim bf16 agg (self loop) + bias + log_softmax ----------------
__global__ void k_agg64(const unsigned short* __restrict__ hw, float* __restrict__ out,
                        const int* __restrict__ offs, const int* __restrict__ csr,
                        const float* __restrict__ dinv2, const float* __restrict__ b2, int N) {
    int gw   = (blockIdx.x * blockDim.x + threadIdx.x) >> 6;
    int lane = threadIdx.x & 63;
    if (gw >= N) return;
    int beg = offs[gw], end = offs[gw + 1];
    float di = dinv2[gw];
    float acc = di * fb(hw[(size_t)gw * 64 + lane]);
    int e = beg;
    for (; e + 8 <= end; e += 8) {
        int s[8];
        #pragma unroll
        for (int j = 0; j < 8; ++j) s[j] = csr[e + j];
        float w[8];
        #pragma unroll
        for (int j = 0; j < 8; ++j) w[j] = dinv2[s[j]];
        unsigned short v[8];
        #pragma unroll
        for (int j = 0; j < 8; ++j) v[j] = hw[(size_t)s[j] * 64 + lane];
        #pragma unroll
        for (int j = 0; j < 8; ++j) acc = fmaf(w[j], fb(v[j]), acc);
    }
    for (; e < end; ++e) {
        int s = csr[e];
        acc = fmaf(dinv2[s], fb(hw[(size_t)s * 64 + lane]), acc);
    }
    acc = di * acc + b2[lane];
    float m = acc;
    #pragma unroll
    for (int o = 32; o > 0; o >>= 1) m = fmaxf(m, __shfl_xor(m, o));
    float ex = expf(acc - m);
    float s = ex;
    #pragma unroll
    for (int o = 32; o > 0; o >>= 1) s += __shfl_xor(s, o);
    out[(size_t)gw * 64 + lane] = acc - m - logf(s);
}

extern "C" void kernel_launch(void* const* d_in, const int* in_sizes, int n_in,
                              void* d_out, int out_size, void* d_ws, size_t ws_size,
                              hipStream_t stream) {
    const float* x    = (const float*)d_in[0];
    const int*   esrc = (const int*)d_in[1];
    const int*   edst = (const int*)d_in[2];
    const float* W1   = (const float*)d_in[3];
    const float* b1   = (const float*)d_in[4];
    const float* W2   = (const float*)d_in[5];
    const float* b2   = (const float*)d_in[6];

    const int N = in_sizes[0] / IN_DIM_C;
    const int E = in_sizes[1];

    char* p = (char*)d_ws;
    auto carve = [&](size_t bytes) -> char* {
        char* r = p; p += (bytes + 255) & ~(size_t)255; return r;
    };
    int*   deg    = (int*)carve((size_t)N * 4);
    int*   offs   = (int*)carve((size_t)(N + 1) * 4);
    float* dinv   = (float*)carve((size_t)N * 4);
    float* dinv2  = (float*)carve((size_t)N * 4);
    int*   counts = (int*)carve((size_t)NBUCK * NBLK * 4);
    int*   sc     = (int*)carve(((size_t)NBUCK * NBLK + 1) * 4);
    int*   part   = (int*)carve(512 * 4);
    unsigned int* spk = (unsigned int*)carve((size_t)E * 4);
    int*   csr    = (int*)carve((size_t)E * 4);
    unsigned short* buf0 = (unsigned short*)carve((size_t)N * 256 * 2); // xbf -> later h
    unsigned short* buf1 = (unsigned short*)carve((size_t)N * 256 * 2); // h1  -> later hw
    unsigned short* buf2 = (unsigned short*)carve((size_t)N * 256 * 2); // h2
    unsigned short* W1p  = (unsigned short*)carve((size_t)IN_DIM_C * HID_DIM_C * 2);
    unsigned short* W2p  = (unsigned short*)carve((size_t)HID_DIM_C * OUT_DIM_C * 2);

    const int NB = (N + 255) / 256;
    const int NC = NBUCK * NBLK;            // 65536 count entries

    // ---- bucket counting-sort CSR build (no global atomics, local writes) ----
    k_hist <<<NBLK, 256, 0, stream>>>(edst, counts, E);
    k_scan1<<<NC / 256, 256, 0, stream>>>(counts, sc, part, NC);
    k_scan2<<<1, 512, 0, stream>>>(part, NC / 256);
    k_scan3b<<<NC / 256, 256, 0, stream>>>(sc, part, NC);
    k_scat <<<NBLK, 256, 0, stream>>>(esrc, edst, sc, spk, E);
    k_csr  <<<NBUCK, 256, 0, stream>>>(spk, sc, csr, offs, deg, N, E);
    k_dinv <<<NB, 256, 0, stream>>>(deg, dinv, dinv2, N);

    // x -> bf16
    int n4 = N * IN_DIM_C / 4;
    k_cvt<<<(n4 + 255) / 256, 256, 0, stream>>>((const float4*)x, (uint2*)buf0, n4);
    // pack weights into MFMA B-fragment layout
    k_packB<<<(IN_DIM_C * HID_DIM_C + 255) / 256, 256, 0, stream>>>(W1, W1p, IN_DIM_C, HID_DIM_C);
    k_packB<<<(HID_DIM_C * OUT_DIM_C + 255) / 256, 256, 0, stream>>>(W2, W2p, HID_DIM_C, OUT_DIM_C);

    const int aggBlocks = (N + 3) / 4;
    // conv1 hop 1: xbf(buf0) -> h1(buf1)
    k_aggbf<<<aggBlocks, 256, 0, stream>>>((const uint2*)buf0, (uint2*)buf1,
                                           offs, csr, dinv, 1.0f, N);
    // conv1 hop 2: h1(buf1) -> h2(buf2), coeff e^-1
    k_aggbf<<<aggBlocks, 256, 0, stream>>>((const uint2*)buf1, (uint2*)buf2,
                                           offs, csr, dinv, EXP_NEG1, N);
    // h = selu(h2 @ W1 + b1) -> buf0 (xbf dead)
    k_mgemm<256><<<(N + 63) / 64, 256, 0, stream>>>(buf2, W1p, b1, buf0, N, HID_DIM_C, 1);
    // hw = h @ W2 (bias deferred) -> buf1 (h1 dead)
    k_mgemm<256><<<(N + 63) / 64, 256, 0, stream>>>(buf0, W2p, nullptr, buf1, N, OUT_DIM_C, 0);
    // out = log_softmax(A2 @ hw + b2)
    k_agg64<<<aggBlocks, 256, 0, stream>>>(buf1, (float*)d_out, offs, csr, dinv2, b2, N);
}

// Round 13
// 906.731 us; speedup vs baseline: 2.1999x; 1.0045x over previous
//
#include <hip/hip_runtime.h>
#include <math.h>

static constexpr int IN_DIM_C  = 256;
static constexpr int HID_DIM_C = 256;
static constexpr int OUT_DIM_C = 64;
static constexpr float EXP_NEG1   = 0.36787944117144233f;
static constexpr float SELU_ALPHA = 1.6732632423543772f;
static constexpr float SELU_SCALE = 1.0507009873554805f;

// bucket sort params: bucket = dst >> BSH (512 nodes per bucket)
static constexpr int NBLK  = 256;   // sort blocks
static constexpr int NBUCK = 256;   // buckets
static constexpr int BSH   = 9;     // log2(nodes per bucket)
static constexpr int BMASK = (1 << BSH) - 1;

typedef __attribute__((ext_vector_type(4))) float f32x4;
typedef __attribute__((ext_vector_type(8))) short bf16x8;

// ---- bf16 helpers (RNE) ----
__device__ __forceinline__ unsigned short bf1(float f) {
    unsigned int u = __float_as_uint(f);
    u = u + 0x7FFFu + ((u >> 16) & 1u);
    return (unsigned short)(u >> 16);
}
__device__ __forceinline__ unsigned int bfpack2(float lo, float hi) {
    return (unsigned int)bf1(lo) | ((unsigned int)bf1(hi) << 16);
}
__device__ __forceinline__ float fb(unsigned short h) {
    return __uint_as_float(((unsigned int)h) << 16);
}

// ---------------- pass 1: per-block bucket histogram ----------------
__global__ __launch_bounds__(256) void k_hist(const int* __restrict__ dst,
                                              int* __restrict__ counts, int E) {
    __shared__ int hist[NBUCK];
    int tid = threadIdx.x, blk = blockIdx.x;
    hist[tid] = 0;
    __syncthreads();
    int ch = (E + NBLK - 1) / NBLK;
    int beg = blk * ch, end = min(beg + ch, E);
    for (int i = beg + tid; i < end; i += 256)
        atomicAdd(&hist[dst[i] >> BSH], 1);
    __syncthreads();
    counts[tid * NBLK + blk] = hist[tid];
}

// ---------------- hierarchical exclusive scan (generic) ----------------
__global__ void k_scan1(const int* __restrict__ in, int* __restrict__ out,
                        int* __restrict__ part, int n) {
    __shared__ int sm[256];
    int tid = threadIdx.x, idx = blockIdx.x * 256 + tid;
    int v = (idx < n) ? in[idx] : 0;
    sm[tid] = v; __syncthreads();
    #pragma unroll
    for (int o = 1; o < 256; o <<= 1) {
        int t = (tid >= o) ? sm[tid - o] : 0;
        __syncthreads();
        sm[tid] += t;
        __syncthreads();
    }
    if (idx < n) out[idx] = sm[tid] - v;
    if (tid == 255) part[blockIdx.x] = sm[255];
}

__global__ void k_scan2(int* __restrict__ part, int NB) {
    __shared__ int sm[512];
    int tid = threadIdx.x;
    int v = (tid < NB) ? part[tid] : 0;
    sm[tid] = v; __syncthreads();
    for (int o = 1; o < 512; o <<= 1) {
        int t = (tid >= o) ? sm[tid - o] : 0;
        __syncthreads();
        sm[tid] += t;
        __syncthreads();
    }
    if (tid < NB) part[tid] = sm[tid] - v;
}

__global__ void k_scan3b(int* __restrict__ v, const int* __restrict__ part, int n) {
    int idx = blockIdx.x * 256 + threadIdx.x;
    if (idx < n) v[idx] += part[idx >> 8];
}

// ---------------- pass 2: scatter edges into bucket-sorted packed array ----------------
__global__ __launch_bounds__(256) void k_scat(const int* __restrict__ src,
                                              const int* __restrict__ dst,
                                              const int* __restrict__ sc,
                                              unsigned int* __restrict__ spk, int E) {
    __shared__ int cur[NBUCK];
    int tid = threadIdx.x, blk = blockIdx.x;
    cur[tid] = sc[tid * NBLK + blk];
    __syncthreads();
    int ch = (E + NBLK - 1) / NBLK;
    int beg = blk * ch, end = min(beg + ch, E);
    for (int i = beg + tid; i < end; i += 256) {
        int d = dst[i];
        int b = d >> BSH;
        int slot = atomicAdd(&cur[b], 1);
        spk[slot] = ((unsigned int)src[i] << BSH) | (unsigned int)(d & BMASK);
    }
}

// ---------------- pass 3: per-bucket CSR finalize ----------------
__global__ __launch_bounds__(256) void k_csr(const unsigned int* __restrict__ spk,
                                             const int* __restrict__ sc,
                                             int* __restrict__ csr,
                                             int* __restrict__ offsG,
                                             int* __restrict__ degG, int N, int E) {
    __shared__ int ldeg[512], loffs[512], sm[256];
    int tid = threadIdx.x, b = blockIdx.x;
    int start = sc[b * NBLK];
    int end   = (b == NBUCK - 1) ? E : sc[(b + 1) * NBLK];
    ldeg[tid] = 0; ldeg[tid + 256] = 0;
    __syncthreads();
    for (int i = start + tid; i < end; i += 256)
        atomicAdd(&ldeg[spk[i] & BMASK], 1);
    __syncthreads();
    int d0 = ldeg[2 * tid], d1 = ldeg[2 * tid + 1];
    int s = d0 + d1;
    sm[tid] = s; __syncthreads();
    #pragma unroll
    for (int o = 1; o < 256; o <<= 1) {
        int t = (tid >= o) ? sm[tid - o] : 0;
        __syncthreads();
        sm[tid] += t;
        __syncthreads();
    }
    int excl = sm[tid] - s;
    loffs[2 * tid] = excl;
    loffs[2 * tid + 1] = excl + d0;
    int node0 = b << BSH;
    int n0 = node0 + 2 * tid, n1 = n0 + 1;
    if (n0 < N) { offsG[n0] = start + excl;      degG[n0] = d0; }
    if (n1 < N) { offsG[n1] = start + excl + d0; degG[n1] = d1; }
    if (b == NBUCK - 1 && tid == 0) offsG[N] = E;
    __syncthreads();
    ldeg[tid] = 0; ldeg[tid + 256] = 0;   // reuse as per-node cursors
    __syncthreads();
    for (int i = start + tid; i < end; i += 256) {
        unsigned int pk = spk[i];
        int n = pk & BMASK;
        int k = atomicAdd(&ldeg[n], 1);
        csr[start + loffs[n] + k] = (int)(pk >> BSH);
    }
}

// ---------------- normalization coefficients ----------------
__global__ void k_dinv(const int* __restrict__ deg, float* __restrict__ dinv,
                       float* __restrict__ dinv2, int N) {
    int i = blockIdx.x * 256 + threadIdx.x;
    if (i < N) {
        int d = deg[i];
        dinv[i]  = (d > 0) ? rsqrtf((float)d) : 0.f;
        dinv2[i] = rsqrtf((float)(d + 1));
    }
}

// ---------------- f32 -> bf16 elementwise ----------------
__global__ void k_cvt(const float4* __restrict__ in, uint2* __restrict__ out, int n4) {
    int i = blockIdx.x * 256 + threadIdx.x;
    if (i < n4) {
        float4 v = in[i];
        uint2 o;
        o.x = bfpack2(v.x, v.y);
        o.y = bfpack2(v.z, v.w);
        out[i] = o;
    }
}

// ---------------- pack W[K][N] f32 -> MFMA B-fragment layout, bf16 ----------------
__global__ void k_packB(const float* __restrict__ W, unsigned short* __restrict__ Bp,
                        int K, int N) {
    int idx = blockIdx.x * 256 + threadIdx.x;
    if (idx >= K * N) return;
    int j = idx & 7;
    int l = (idx >> 3) & 63;
    int rest = idx >> 9;
    int KC = K >> 5;
    int c = rest % KC, t = rest / KC;
    int k = c * 32 + ((l >> 4) << 3) + j;
    int n = t * 16 + (l & 15);
    Bp[idx] = bf1(W[(size_t)k * N + n]);
}

// ---------------- 256-dim aggregation, HALF-DIM pass (256B row-halves) ----------------
// Pass `half` covers bf16 dims [half*128, half*128+128) = uints [half*64 .. +64).
// Footprint per pass = 25.6MB (vs 51.2) -> better per-XCD L2 hit rate on the
// bytes-bound miss path (rounds 1/4/11: hop time scales with miss bytes).
__global__ void k_agghalf(const unsigned int* __restrict__ xin,  // row = 128 uints
                          unsigned int* __restrict__ yout,
                          const int* __restrict__ offs, const int* __restrict__ csr,
                          const float* __restrict__ dinv, float scl, int N, int half) {
    int gw   = (blockIdx.x * blockDim.x + threadIdx.x) >> 6;
    int lane = threadIdx.x & 63;
    if (gw >= N) return;
    int beg = offs[gw], end = offs[gw + 1];
    int off = half * 64 + lane;               // uint offset within row
    float a0 = 0.f, a1 = 0.f;
    int e = beg;
    for (; e + 8 <= end; e += 8) {
        int s[8];
        #pragma unroll
        for (int j = 0; j < 8; ++j) s[j] = csr[e + j];
        float w[8];
        #pragma unroll
        for (int j = 0; j < 8; ++j) w[j] = dinv[s[j]];
        unsigned int v[8];
        #pragma unroll
        for (int j = 0; j < 8; ++j) v[j] = xin[(size_t)s[j] * 128 + off];
        #pragma unroll
        for (int j = 0; j < 8; ++j) {
            a0 = fmaf(w[j], __uint_as_float(v[j] << 16), a0);
            a1 = fmaf(w[j], __uint_as_float(v[j] & 0xFFFF0000u), a1);
        }
    }
    for (; e < end; ++e) {
        int s = csr[e];
        float w = dinv[s];
        unsigned int v = xin[(size_t)s * 128 + off];
        a0 = fmaf(w, __uint_as_float(v << 16), a0);
        a1 = fmaf(w, __uint_as_float(v & 0xFFFF0000u), a1);
    }
    float c = scl * dinv[gw];
    yout[(size_t)gw * 128 + off] = bfpack2(a0 * c, a1 * c);
}

// ---------------- fused MFMA GEMM1(+bias+selu) -> LDS -> GEMM2 ----------------
__device__ __forceinline__ float selu_f(float v) {
    return v > 0.f ? SELU_SCALE * v : SELU_SCALE * SELU_ALPHA * expm1f(v);
}

// hw[M][64] = selu(A[M][256] @ W1 + b1) @ W2     (b2 deferred to k_agg64)
__global__ __launch_bounds__(256) void k_fgemm(
        const unsigned short* __restrict__ A,    // [M][256] bf16
        const unsigned short* __restrict__ B1p,  // W1 packed (KC=8, NT=16)
        const float* __restrict__ b1,
        const unsigned short* __restrict__ B2p,  // W2 packed (KC=8, NT=4)
        unsigned short* __restrict__ Cb,         // [M][64] bf16
        int M) {
    // padded LDS: row stride 264 shorts (528B) -> 4-bank rotation per row,
    // 2-way max conflict on the b128 fragment reads (free per m136)
    __shared__ unsigned short hs[64][264];
    int wid  = threadIdx.x >> 6;
    int lane = threadIdx.x & 63;
    int m0   = blockIdx.x * 64 + wid * 16;
    int arow = m0 + (lane & 15);
    int kg   = lane >> 4;
    bf16x8 zf = {0, 0, 0, 0, 0, 0, 0, 0};
    bf16x8 af[8];
    bool valid = arow < M;
    #pragma unroll
    for (int c = 0; c < 8; ++c) {
        if (valid) af[c] = *(const bf16x8*)&A[(size_t)arow * 256 + c * 32 + kg * 8];
        else       af[c] = zf;
    }
    // GEMM1: 16 col-tiles of 16; h tile -> LDS (bias+selu applied)
    #pragma unroll 4
    for (int t = 0; t < 16; ++t) {
        f32x4 acc = {0.f, 0.f, 0.f, 0.f};
        #pragma unroll
        for (int c = 0; c < 8; ++c) {
            bf16x8 bfv = *(const bf16x8*)&B1p[(((size_t)t * 8 + c) * 64 + lane) * 8];
            acc = __builtin_amdgcn_mfma_f32_16x16x32_bf16(af[c], bfv, acc, 0, 0, 0);
        }
        int n = t * 16 + (lane & 15);
        float bv = b1[n];
        #pragma unroll
        for (int r = 0; r < 4; ++r) {
            int rl = wid * 16 + (lane >> 4) * 4 + r;   // row within block tile
            hs[rl][n] = bf1(selu_f(acc[r] + bv));
        }
    }
    __syncthreads();
    // GEMM2: A-fragments from LDS h tile
    bf16x8 af2[8];
    #pragma unroll
    for (int c = 0; c < 8; ++c)
        af2[c] = *(const bf16x8*)&hs[wid * 16 + (lane & 15)][c * 32 + kg * 8];
    #pragma unroll
    for (int t = 0; t < 4; ++t) {
        f32x4 acc = {0.f, 0.f, 0.f, 0.f};
        #pragma unroll
        for (int c = 0; c < 8; ++c) {
            bf16x8 bfv = *(const bf16x8*)&B2p[(((size_t)t * 8 + c) * 64 + lane) * 8];
            acc = __builtin_amdgcn_mfma_f32_16x16x32_bf16(af2[c], bfv, acc, 0, 0, 0);
        }
        int n = t * 16 + (lane & 15);
        #pragma unroll
        for (int r = 0; r < 4; ++r) {
            int m = m0 + (lane >> 4) * 4 + r;
            if (m < M) Cb[(size_t)m * 64 + n] = bf1(acc[r]);
        }
    }
}

// ---------------- final: 64-dim bf16 agg (self loop) + bias + log_softmax ----------------
__global__ void k_agg64(const unsigned short* __restrict__ hw, float* __restrict__ out,
                        const int* __restrict__ offs, const int* __restrict__ csr,
                        const float* __restrict__ dinv2, const float* __restrict__ b2, int N) {
    int gw   = (blockIdx.x * blockDim.x + threadIdx.x) >> 6;
    int lane = threadIdx.x & 63;
    if (gw >= N) return;
    int beg = offs[gw], end = offs[gw + 1];
    float di = dinv2[gw];
    float acc = di * fb(hw[(size_t)gw * 64 + lane]);
    int e = beg;
    for (; e + 8 <= end; e += 8) {
        int s[8];
        #pragma unroll
        for (int j = 0; j < 8; ++j) s[j] = csr[e + j];
        float w[8];
        #pragma unroll
        for (int j = 0; j < 8; ++j) w[j] = dinv2[s[j]];
        unsigned short v[8];
        #pragma unroll
        for (int j = 0; j < 8; ++j) v[j] = hw[(size_t)s[j] * 64 + lane];
        #pragma unroll
        for (int j = 0; j < 8; ++j) acc = fmaf(w[j], fb(v[j]), acc);
    }
    for (; e < end; ++e) {
        int s = csr[e];
        acc = fmaf(dinv2[s], fb(hw[(size_t)s * 64 + lane]), acc);
    }
    acc = di * acc + b2[lane];
    float m = acc;
    #pragma unroll
    for (int o = 32; o > 0; o >>= 1) m = fmaxf(m, __shfl_xor(m, o));
    float ex = expf(acc - m);
    float s = ex;
    #pragma unroll
    for (int o = 32; o > 0; o >>= 1) s += __shfl_xor(s, o);
    out[(size_t)gw * 64 + lane] = acc - m - logf(s);
}

extern "C" void kernel_launch(void* const* d_in, const int* in_sizes, int n_in,
                              void* d_out, int out_size, void* d_ws, size_t ws_size,
                              hipStream_t stream) {
    const float* x    = (const float*)d_in[0];
    const int*   esrc = (const int*)d_in[1];
    const int*   edst = (const int*)d_in[2];
    const float* W1   = (const float*)d_in[3];
    const float* b1   = (const float*)d_in[4];
    const float* W2   = (const float*)d_in[5];
    const float* b2   = (const float*)d_in[6];

    const int N = in_sizes[0] / IN_DIM_C;
    const int E = in_sizes[1];

    char* p = (char*)d_ws;
    auto carve = [&](size_t bytes) -> char* {
        char* r = p; p += (bytes + 255) & ~(size_t)255; return r;
    };
    int*   deg    = (int*)carve((size_t)N * 4);
    int*   offs   = (int*)carve((size_t)(N + 1) * 4);
    float* dinv   = (float*)carve((size_t)N * 4);
    float* dinv2  = (float*)carve((size_t)N * 4);
    int*   counts = (int*)carve((size_t)NBUCK * NBLK * 4);
    int*   sc     = (int*)carve(((size_t)NBUCK * NBLK + 1) * 4);
    int*   part   = (int*)carve(512 * 4);
    unsigned int* spk = (unsigned int*)carve((size_t)E * 4);
    int*   csr    = (int*)carve((size_t)E * 4);
    unsigned short* buf0 = (unsigned short*)carve((size_t)N * 256 * 2); // xbf
    unsigned short* buf1 = (unsigned short*)carve((size_t)N * 256 * 2); // h1 -> later hw
    unsigned short* buf2 = (unsigned short*)carve((size_t)N * 256 * 2); // h2
    unsigned short* W1p  = (unsigned short*)carve((size_t)IN_DIM_C * HID_DIM_C * 2);
    unsigned short* W2p  = (unsigned short*)carve((size_t)HID_DIM_C * OUT_DIM_C * 2);

    const int NB = (N + 255) / 256;
    const int NC = NBUCK * NBLK;

    // ---- bucket counting-sort CSR build ----
    k_hist <<<NBLK, 256, 0, stream>>>(edst, counts, E);
    k_scan1<<<NC / 256, 256, 0, stream>>>(counts, sc, part, NC);
    k_scan2<<<1, 512, 0, stream>>>(part, NC / 256);
    k_scan3b<<<NC / 256, 256, 0, stream>>>(sc, part, NC);
    k_scat <<<NBLK, 256, 0, stream>>>(esrc, edst, sc, spk, E);
    k_csr  <<<NBUCK, 256, 0, stream>>>(spk, sc, csr, offs, deg, N, E);
    k_dinv <<<NB, 256, 0, stream>>>(deg, dinv, dinv2, N);

    // x -> bf16; pack weights
    int n4 = N * IN_DIM_C / 4;
    k_cvt<<<(n4 + 255) / 256, 256, 0, stream>>>((const float4*)x, (uint2*)buf0, n4);
    k_packB<<<(IN_DIM_C * HID_DIM_C + 255) / 256, 256, 0, stream>>>(W1, W1p, IN_DIM_C, HID_DIM_C);
    k_packB<<<(HID_DIM_C * OUT_DIM_C + 255) / 256, 256, 0, stream>>>(W2, W2p, HID_DIM_C, OUT_DIM_C);

    const int aggBlocks = (N + 3) / 4;     // 4 waves (nodes) per 256-thread block
    // conv1 hop 1: xbf(buf0) -> h1(buf1), two half-dim passes
    k_agghalf<<<aggBlocks, 256, 0, stream>>>((const unsigned int*)buf0, (unsigned int*)buf1,
                                             offs, csr, dinv, 1.0f, N, 0);
    k_agghalf<<<aggBlocks, 256, 0, stream>>>((const unsigned int*)buf0, (unsigned int*)buf1,
                                             offs, csr, dinv, 1.0f, N, 1);
    // conv1 hop 2: h1(buf1) -> h2(buf2), coeff e^-1, two half-dim passes
    k_agghalf<<<aggBlocks, 256, 0, stream>>>((const unsigned int*)buf1, (unsigned int*)buf2,
                                             offs, csr, dinv, EXP_NEG1, N, 0);
    k_agghalf<<<aggBlocks, 256, 0, stream>>>((const unsigned int*)buf1, (unsigned int*)buf2,
                                             offs, csr, dinv, EXP_NEG1, N, 1);
    // hw = selu(h2 @ W1 + b1) @ W2 -> buf1 (fused, h1 dead)
    k_fgemm<<<(N + 63) / 64, 256, 0, stream>>>(buf2, W1p, b1, W2p, buf1, N);
    // out = log_softmax(A2 @ hw + b2)
    k_agg64<<<aggBlocks, 256, 0, stream>>>(buf1, (float*)d_out, offs, csr, dinv2, b2, N);
}